// Round 1
// baseline (4241.306 us; speedup 1.0000x reference)
//
#include <hip/hip_runtime.h>
#include <hip/hip_bf16.h>

#define HIDDEN 1152
#define NUM_HEADS 16
#define HEAD_DIM 72
#define BATCH 8
#define SEQ 1024
#define MROWS (BATCH * SEQ)   // 8192

// ---------------- GEMM: C[M,N] = A[M,K] @ W[K,N] + bias[N] ----------------
#define BM 64
#define BN 64
#define BK 16

__global__ __launch_bounds__(256) void gemm_bias_kernel(
    const float* __restrict__ A, const float* __restrict__ W,
    const float* __restrict__ bias, float* __restrict__ C,
    int M, int N, int K) {
  __shared__ float As[BK][BM + 1];
  __shared__ float Ws[BK][BN + 1];

  const int bx = blockIdx.x;  // N tile
  const int by = blockIdx.y;  // M tile
  const int tid = threadIdx.x;
  const int tx = tid % 16;    // 16x16 threads, each 4x4 outputs
  const int ty = tid / 16;

  const int row0 = by * BM;
  const int col0 = bx * BN;

  float acc[4][4] = {};

  for (int k0 = 0; k0 < K; k0 += BK) {
    // Load A tile (BM x BK) transposed into As[c][r]
#pragma unroll
    for (int i = tid; i < BM * BK; i += 256) {
      int r = i / BK, c = i % BK;
      As[c][r] = A[(size_t)(row0 + r) * K + (k0 + c)];
    }
    // Load W tile (BK x BN)
#pragma unroll
    for (int i = tid; i < BK * BN; i += 256) {
      int r = i / BN, c = i % BN;
      Ws[r][c] = W[(size_t)(k0 + r) * N + (col0 + c)];
    }
    __syncthreads();

#pragma unroll
    for (int kk = 0; kk < BK; ++kk) {
      float a[4], w[4];
#pragma unroll
      for (int i = 0; i < 4; ++i) a[i] = As[kk][ty * 4 + i];
#pragma unroll
      for (int j = 0; j < 4; ++j) w[j] = Ws[kk][tx * 4 + j];
#pragma unroll
      for (int i = 0; i < 4; ++i)
#pragma unroll
        for (int j = 0; j < 4; ++j) acc[i][j] += a[i] * w[j];
    }
    __syncthreads();
  }

#pragma unroll
  for (int i = 0; i < 4; ++i) {
    int r = row0 + ty * 4 + i;
#pragma unroll
    for (int j = 0; j < 4; ++j) {
      int c = col0 + tx * 4 + j;
      C[(size_t)r * N + c] = acc[i][j] + bias[c];
    }
  }
}

// ---------------- Attention: one thread per (b, h, q) row ----------------
// Q,K,V stored as [B, S, H] (head h occupies columns h*72 .. h*72+71).
// O written in-place over Q (each thread reads only its own Q row first).
__global__ __launch_bounds__(256) void attn_kernel(
    const float* __restrict__ K, const float* __restrict__ V,
    float* __restrict__ QO) {
  const int idx = blockIdx.x * 256 + threadIdx.x;  // [B*NH*S]
  const int q = idx & (SEQ - 1);
  const int bh = idx >> 10;
  const int h = bh & (NUM_HEADS - 1);
  const int b = bh >> 4;

  const float scale = 0.11785113019775793f;  // 1/sqrt(72)
  const size_t base = ((size_t)b * SEQ) * HIDDEN + (size_t)h * HEAD_DIM;

  float* qrow = QO + base + (size_t)q * HIDDEN;
  float qv[HEAD_DIM];
#pragma unroll
  for (int d = 0; d < HEAD_DIM; ++d) qv[d] = qrow[d] * scale;

  float m = -INFINITY, l = 0.f;
  float acc[HEAD_DIM] = {};

  const float* Kb = K + base;
  const float* Vb = V + base;

  for (int kk = 0; kk < SEQ; ++kk) {
    const float* krow = Kb + (size_t)kk * HIDDEN;
    float s = 0.f;
#pragma unroll
    for (int d = 0; d < HEAD_DIM; ++d) s += qv[d] * krow[d];

    if (s > m) {
      float corr = __expf(m - s);
      l *= corr;
#pragma unroll
      for (int d = 0; d < HEAD_DIM; ++d) acc[d] *= corr;
      m = s;
    }
    float p = __expf(s - m);
    l += p;
    const float* vrow = Vb + (size_t)kk * HIDDEN;
#pragma unroll
    for (int d = 0; d < HEAD_DIM; ++d) acc[d] += p * vrow[d];
  }

  const float inv = 1.f / l;
#pragma unroll
  for (int d = 0; d < HEAD_DIM; ++d) qrow[d] = acc[d] * inv;
}

// ---------------- launch ----------------
extern "C" void kernel_launch(void* const* d_in, const int* in_sizes, int n_in,
                              void* d_out, int out_size, void* d_ws, size_t ws_size,
                              hipStream_t stream) {
  const float* x  = (const float*)d_in[0];
  const float* wq = (const float*)d_in[1];
  const float* bq = (const float*)d_in[2];
  const float* wk = (const float*)d_in[3];
  const float* bk = (const float*)d_in[4];
  const float* wv = (const float*)d_in[5];
  const float* bv = (const float*)d_in[6];
  const float* wo = (const float*)d_in[7];
  const float* bo = (const float*)d_in[8];
  float* out = (float*)d_out;

  const size_t bufElems = (size_t)MROWS * HIDDEN;  // 9,437,184
  float* Q = (float*)d_ws;            // later overwritten with attention output
  float* Kb = Q + bufElems;
  float* Vb = Kb + bufElems;

  dim3 gemmGrid(HIDDEN / BN, MROWS / BM);  // (18, 128)
  dim3 gemmBlock(256);

  gemm_bias_kernel<<<gemmGrid, gemmBlock, 0, stream>>>(x, wq, bq, Q,  MROWS, HIDDEN, HIDDEN);
  gemm_bias_kernel<<<gemmGrid, gemmBlock, 0, stream>>>(x, wk, bk, Kb, MROWS, HIDDEN, HIDDEN);
  gemm_bias_kernel<<<gemmGrid, gemmBlock, 0, stream>>>(x, wv, bv, Vb, MROWS, HIDDEN, HIDDEN);

  attn_kernel<<<(BATCH * NUM_HEADS * SEQ) / 256, 256, 0, stream>>>(Kb, Vb, Q);

  gemm_bias_kernel<<<gemmGrid, gemmBlock, 0, stream>>>(Q, wo, bo, out, MROWS, HIDDEN, HIDDEN);
}

// Round 2
// 398.537 us; speedup vs baseline: 10.6422x; 10.6422x over previous
//
#include <hip/hip_runtime.h>
#include <hip/hip_bf16.h>

#define HIDDEN 1152
#define NUM_HEADS 16
#define BATCH 8
#define SEQ 1024
#define MROWS (BATCH * SEQ)  // 8192

typedef __attribute__((ext_vector_type(8))) short short8;
typedef __attribute__((ext_vector_type(4))) float f32x4;

__device__ inline short f2bf(float x) {
  unsigned u = __float_as_uint(x);
  unsigned r = (u + 0x7FFFu + ((u >> 16) & 1u)) >> 16;
  return (short)(r & 0xFFFFu);
}

__device__ inline void gload16(const void* g, void* l) {
  __builtin_amdgcn_global_load_lds(
      (const __attribute__((address_space(1))) void*)g,
      (__attribute__((address_space(3))) void*)l, 16, 0, 0);
}

// ---------------- x fp32 -> bf16 ----------------
__global__ __launch_bounds__(256) void k_cvtx(const float* __restrict__ X,
                                              short* __restrict__ Xb) {
  const size_t base = ((size_t)blockIdx.x * 256 + threadIdx.x) * 8;
  float4 a = *(const float4*)(X + base);
  float4 b = *(const float4*)(X + base + 4);
  short8 o = {f2bf(a.x), f2bf(a.y), f2bf(a.z), f2bf(a.w),
              f2bf(b.x), f2bf(b.y), f2bf(b.z), f2bf(b.w)};
  *(short8*)(Xb + base) = o;
}

// ---------------- W [K,N] fp32 -> Wt [N,K] bf16 ----------------
__global__ __launch_bounds__(256) void k_cvtw(const float* __restrict__ W0,
                                              const float* __restrict__ W1,
                                              const float* __restrict__ W2,
                                              const float* __restrict__ W3,
                                              short* __restrict__ Wt) {
  __shared__ float T[64][65];
  const float* W = (blockIdx.z == 0) ? W0 : (blockIdx.z == 1) ? W1
                 : (blockIdx.z == 2) ? W2 : W3;
  short* dst = Wt + (size_t)blockIdx.z * HIDDEN * HIDDEN;
  const int n0 = blockIdx.x * 64, k0 = blockIdx.y * 64;
  const int tid = threadIdx.x;
  for (int t = tid; t < 4096; t += 256) {
    int r = t >> 6, c = t & 63;
    T[r][c] = W[(size_t)(k0 + r) * HIDDEN + n0 + c];
  }
  __syncthreads();
  for (int t = tid; t < 4096; t += 256) {
    int r = t >> 6, c = t & 63;
    dst[(size_t)(n0 + r) * HIDDEN + k0 + c] = f2bf(T[c][r]);
  }
}

// ---------------- GEMM: C = A[M,K]bf16 @ Wt[N,K]bf16^T + bias ----------------
// OUTKIND 0: bf16 per-head layout [B,H,S,72];  OUTKIND 1: fp32 [M,N]
template <int OUTKIND>
__global__ __launch_bounds__(256) void k_gemm(const short* __restrict__ A,
                                              const short* __restrict__ Bt,
                                              const float* __restrict__ bias,
                                              void* __restrict__ Cout) {
  __shared__ short As[8192];  // [128][64] bf16, XOR-swizzled
  __shared__ short Bs[8192];
  const int tid = threadIdx.x;
  const int lane = tid & 63;
  const int wid = tid >> 6;
  const int wr = wid >> 1, wc = wid & 1;
  const int row0 = blockIdx.y << 7;
  const int col0 = blockIdx.x << 7;
  const int l15 = lane & 15, lh = lane >> 4;
  const int lr8 = lane >> 3;
  const int csrc = ((lane & 7) ^ lr8) << 3;  // pre-swizzled source col (shorts)

  const f32x4 fz = {0.f, 0.f, 0.f, 0.f};
  f32x4 acc[4][4];
#pragma unroll
  for (int m = 0; m < 4; ++m)
#pragma unroll
    for (int n = 0; n < 4; ++n) acc[m][n] = fz;

  for (int k0 = 0; k0 < HIDDEN; k0 += 64) {
#pragma unroll
    for (int i = 0; i < 4; ++i) {
      const int chunk = (wid << 2) + i;
      const int r = (chunk << 3) + lr8;
      gload16(A + (size_t)(row0 + r) * HIDDEN + k0 + csrc, (void*)(As + (chunk << 9)));
      gload16(Bt + (size_t)(col0 + r) * HIDDEN + k0 + csrc, (void*)(Bs + (chunk << 9)));
    }
    __syncthreads();
#pragma unroll
    for (int ks = 0; ks < 2; ++ks) {
      short8 af[4], bfr[4];
#pragma unroll
      for (int m = 0; m < 4; ++m) {
        const int r = (wr << 6) + (m << 4) + l15;
        const int off = ((ks << 6) + (lh << 4)) ^ ((r & 7) << 4);
        af[m] = *(const short8*)((const char*)As + r * 128 + off);
      }
#pragma unroll
      for (int n = 0; n < 4; ++n) {
        const int r = (wc << 6) + (n << 4) + l15;
        const int off = ((ks << 6) + (lh << 4)) ^ ((r & 7) << 4);
        bfr[n] = *(const short8*)((const char*)Bs + r * 128 + off);
      }
#pragma unroll
      for (int m = 0; m < 4; ++m)
#pragma unroll
        for (int n = 0; n < 4; ++n)
          acc[m][n] = __builtin_amdgcn_mfma_f32_16x16x32_bf16(af[m], bfr[n], acc[m][n], 0, 0, 0);
    }
    __syncthreads();
  }

  if (OUTKIND == 0) {
    short* C = (short*)Cout;
#pragma unroll
    for (int n = 0; n < 4; ++n) {
      const int c = col0 + (wc << 6) + (n << 4) + l15;
      const int h = c / 72;
      const int d = c - h * 72;
      const float bv = bias[c];
#pragma unroll
      for (int m = 0; m < 4; ++m)
#pragma unroll
        for (int i = 0; i < 4; ++i) {
          const int r = row0 + (wr << 6) + (m << 4) + (lh << 2) + i;
          const int b = r >> 10, s = r & 1023;
          C[(size_t)((((b << 4) + h) << 10) + s) * 72 + d] = f2bf(acc[m][n][i] + bv);
        }
    }
  } else {
    float* C = (float*)Cout;
#pragma unroll
    for (int n = 0; n < 4; ++n) {
      const int c = col0 + (wc << 6) + (n << 4) + l15;
      const float bv = bias[c];
#pragma unroll
      for (int m = 0; m < 4; ++m)
#pragma unroll
        for (int i = 0; i < 4; ++i) {
          const int r = row0 + (wr << 6) + (m << 4) + (lh << 2) + i;
          C[(size_t)r * HIDDEN + c] = acc[m][n][i] + bv;
        }
    }
  }
}

// ---------------- V [BH,1024,72] -> Vt [BH,80,1024] (rows 72..79 = 0) --------
__global__ __launch_bounds__(256) void k_vtrans(const short* __restrict__ V,
                                                short* __restrict__ Vt) {
  __shared__ short T[128 * 80];  // [s][d], stride 80 shorts
  const int tid = threadIdx.x;
  const int s0 = blockIdx.x * 128;
  const int bh = blockIdx.y;
  const size_t vbase = (size_t)bh * SEQ * 72;
  for (int t = tid; t < 128 * 9; t += 256) {
    int r = t / 9, ch = t - r * 9;
    *(short8*)(T + r * 80 + ch * 8) =
        *(const short8*)(V + vbase + (size_t)(s0 + r) * 72 + ch * 8);
  }
  __syncthreads();
  const size_t obase = (size_t)bh * 80 * 1024;
  const short8 sz = {0, 0, 0, 0, 0, 0, 0, 0};
  for (int t = tid; t < 80 * 16; t += 256) {
    int sc = t / 80, d = t - sc * 80;
    short8 v = sz;
    if (d < 72) {
#pragma unroll
      for (int j = 0; j < 8; ++j) v[j] = T[(sc * 8 + j) * 80 + d];
    }
    *(short8*)(Vt + obase + (size_t)d * 1024 + s0 + sc * 8) = v;
  }
}

// ---------------- Flash attention (bf16 MFMA) ----------------
// grid: (8 q-tiles, 128 bh). 4 waves x 32 q-rows. KB=64, hd padded to 96.
__global__ __launch_bounds__(256) void k_attn(const short* __restrict__ Qg,
                                              const short* __restrict__ Kg,
                                              const short* __restrict__ Vt,
                                              short* __restrict__ Og) {
  __shared__ short Ks[64 * 120];   // [key][hd], stride 120 shorts (240 B)
  __shared__ short Vs[80 * 72];    // [d][key], stride 72 shorts (144 B)
  __shared__ short Ps[4 * 32 * 72];  // per-wave [32 q][64 k], stride 72
  const int tid = threadIdx.x, lane = tid & 63, wid = tid >> 6;
  const int l15 = lane & 15, lh = lane >> 4;
  const int q0 = blockIdx.x << 7;
  const int bh = blockIdx.y;
  const size_t qkbase = (size_t)bh * SEQ * 72;
  const float sc = 0.11785113019775793f;  // 1/sqrt(72)
  const short8 sz = {0, 0, 0, 0, 0, 0, 0, 0};
  const f32x4 fz = {0.f, 0.f, 0.f, 0.f};

  // Q fragments in registers (reused over all K tiles)
  short8 qf[2][3];
#pragma unroll
  for (int m = 0; m < 2; ++m)
#pragma unroll
    for (int ks = 0; ks < 3; ++ks) {
      const int row = q0 + wid * 32 + m * 16 + l15;
      const int e0 = ks * 32 + lh * 8;
      if (e0 < 72)
        qf[m][ks] = *(const short8*)(Qg + qkbase + (size_t)row * 72 + e0);
      else
        qf[m][ks] = sz;
    }

  float mrun[2][4], lrun[2][4];
  f32x4 oacc[2][5];
#pragma unroll
  for (int m = 0; m < 2; ++m) {
#pragma unroll
    for (int i = 0; i < 4; ++i) { mrun[m][i] = -1e30f; lrun[m][i] = 0.f; }
#pragma unroll
    for (int no = 0; no < 5; ++no) oacc[m][no] = fz;
  }

  for (int kt = 0; kt < 16; ++kt) {
    // stage K tile (zero-pad cols 72..95)
    for (int t = tid; t < 768; t += 256) {
      int r = t / 12, ch = t - r * 12;
      short8 v = sz;
      if (ch < 9)
        v = *(const short8*)(Kg + qkbase + (size_t)(kt * 64 + r) * 72 + ch * 8);
      *(short8*)(Ks + r * 120 + ch * 8) = v;
    }
    // stage Vt tile
    for (int t = tid; t < 640; t += 256) {
      int d = t >> 3, ch = t & 7;
      short8 v = *(const short8*)(Vt + (size_t)bh * 81920 + (size_t)d * 1024 +
                                  kt * 64 + ch * 8);
      *(short8*)(Vs + d * 72 + ch * 8) = v;
    }
    __syncthreads();

    // QK^T
    f32x4 sa[2][4];
#pragma unroll
    for (int m = 0; m < 2; ++m)
#pragma unroll
      for (int n = 0; n < 4; ++n) sa[m][n] = fz;
#pragma unroll
    for (int ks = 0; ks < 3; ++ks) {
      short8 kf[4];
#pragma unroll
      for (int n = 0; n < 4; ++n)
        kf[n] = *(const short8*)(Ks + (n * 16 + l15) * 120 + ks * 32 + lh * 8);
#pragma unroll
      for (int m = 0; m < 2; ++m)
#pragma unroll
        for (int n = 0; n < 4; ++n)
          sa[m][n] = __builtin_amdgcn_mfma_f32_16x16x32_bf16(qf[m][ks], kf[n], sa[m][n], 0, 0, 0);
    }

    // online softmax + P -> LDS (bf16)
#pragma unroll
    for (int m = 0; m < 2; ++m) {
      float corr[4];
#pragma unroll
      for (int i = 0; i < 4; ++i) {
        float mx = fmaxf(fmaxf(sa[m][0][i], sa[m][1][i]),
                         fmaxf(sa[m][2][i], sa[m][3][i]));
#pragma unroll
        for (int off = 1; off < 16; off <<= 1) mx = fmaxf(mx, __shfl_xor(mx, off));
        const float nm = fmaxf(mrun[m][i], mx);
        const float co = __expf((mrun[m][i] - nm) * sc);
        float ps = 0.f;
#pragma unroll
        for (int n = 0; n < 4; ++n) {
          float p = __expf((sa[m][n][i] - nm) * sc);
          sa[m][n][i] = p;
          ps += p;
        }
#pragma unroll
        for (int off = 1; off < 16; off <<= 1) ps += __shfl_xor(ps, off);
        lrun[m][i] = lrun[m][i] * co + ps;
        mrun[m][i] = nm;
        corr[i] = co;
      }
      const f32x4 cv = {corr[0], corr[1], corr[2], corr[3]};
#pragma unroll
      for (int no = 0; no < 5; ++no) oacc[m][no] *= cv;
#pragma unroll
      for (int n = 0; n < 4; ++n)
#pragma unroll
        for (int i = 0; i < 4; ++i)
          Ps[wid * 2304 + (m * 16 + lh * 4 + i) * 72 + n * 16 + l15] =
              f2bf(sa[m][n][i]);
    }

    // PV
#pragma unroll
    for (int ks = 0; ks < 2; ++ks) {
      short8 pa[2], vb[5];
#pragma unroll
      for (int m = 0; m < 2; ++m)
        pa[m] = *(const short8*)(Ps + wid * 2304 + (m * 16 + l15) * 72 + ks * 32 + lh * 8);
#pragma unroll
      for (int no = 0; no < 5; ++no)
        vb[no] = *(const short8*)(Vs + (no * 16 + l15) * 72 + ks * 32 + lh * 8);
#pragma unroll
      for (int m = 0; m < 2; ++m)
#pragma unroll
        for (int no = 0; no < 5; ++no)
          oacc[m][no] = __builtin_amdgcn_mfma_f32_16x16x32_bf16(pa[m], vb[no], oacc[m][no], 0, 0, 0);
    }
    __syncthreads();
  }

  // epilogue: O / l, write bf16 [B,S,1152]
  const int b = bh >> 4, h = bh & 15;
#pragma unroll
  for (int m = 0; m < 2; ++m)
#pragma unroll
    for (int no = 0; no < 5; ++no) {
      const int d = no * 16 + l15;
      if (d < 72) {
#pragma unroll
        for (int i = 0; i < 4; ++i) {
          const int s = q0 + wid * 32 + m * 16 + lh * 4 + i;
          Og[(size_t)(b * 1024 + s) * HIDDEN + h * 72 + d] =
              f2bf(oacc[m][no][i] / lrun[m][i]);
        }
      }
    }
}

// ---------------- launch ----------------
extern "C" void kernel_launch(void* const* d_in, const int* in_sizes, int n_in,
                              void* d_out, int out_size, void* d_ws, size_t ws_size,
                              hipStream_t stream) {
  const float* x  = (const float*)d_in[0];
  const float* wq = (const float*)d_in[1];
  const float* bq = (const float*)d_in[2];
  const float* wk = (const float*)d_in[3];
  const float* bk = (const float*)d_in[4];
  const float* wv = (const float*)d_in[5];
  const float* bv = (const float*)d_in[6];
  const float* wo = (const float*)d_in[7];
  const float* bo = (const float*)d_in[8];

  char* ws = (char*)d_ws;
  short* xb = (short*)ws;                                   // 18,874,368 B (also attn out)
  short* wT = (short*)(ws + 18874368);                      // 4 x 2,654,208 B
  short* Qb = (short*)(ws + 18874368 + 10616832);
  short* Kb = Qb + 9437184;
  short* Vb = Kb + 9437184;
  short* Vt = Vb + 9437184;                                 // 20,971,520 B
  const size_t WSZ = (size_t)HIDDEN * HIDDEN;               // 1,327,104

  k_cvtx<<<4608, 256, 0, stream>>>(x, xb);
  k_cvtw<<<dim3(18, 18, 4), 256, 0, stream>>>(wq, wk, wv, wo, wT);

  dim3 gg(9, 64);
  k_gemm<0><<<gg, 256, 0, stream>>>(xb, wT + 0 * WSZ, bq, (void*)Qb);
  k_gemm<0><<<gg, 256, 0, stream>>>(xb, wT + 1 * WSZ, bk, (void*)Kb);
  k_gemm<0><<<gg, 256, 0, stream>>>(xb, wT + 2 * WSZ, bv, (void*)Vb);

  k_vtrans<<<dim3(8, 128), 256, 0, stream>>>(Vb, Vt);
  k_attn<<<dim3(8, 128), 256, 0, stream>>>(Qb, Kb, Vt, xb);

  k_gemm<1><<<gg, 256, 0, stream>>>(xb, wT + 3 * WSZ, bo, d_out);
}

// Round 3
// 238.284 us; speedup vs baseline: 17.7994x; 1.6725x over previous
//
#include <hip/hip_runtime.h>
#include <hip/hip_bf16.h>

#define HIDDEN 1152
#define NUM_HEADS 16
#define BATCH 8
#define SEQ 1024
#define MROWS (BATCH * SEQ)  // 8192
#define KSTRIDE 104          // padded K row length (shorts)

typedef __attribute__((ext_vector_type(8))) short short8;
typedef __attribute__((ext_vector_type(4))) float f32x4;

__device__ inline short f2bf(float x) {
  unsigned u = __float_as_uint(x);
  unsigned r = (u + 0x7FFFu + ((u >> 16) & 1u)) >> 16;
  return (short)(r & 0xFFFFu);
}

__device__ inline void gload16(const void* g, void* l) {
  __builtin_amdgcn_global_load_lds(
      (const __attribute__((address_space(1))) void*)g,
      (__attribute__((address_space(3))) void*)l, 16, 0, 0);
}

// ---------------- x fp32 -> bf16 ----------------
__global__ __launch_bounds__(256) void k_cvtx(const float* __restrict__ X,
                                              short* __restrict__ Xb) {
  const size_t base = ((size_t)blockIdx.x * 256 + threadIdx.x) * 8;
  float4 a = *(const float4*)(X + base);
  float4 b = *(const float4*)(X + base + 4);
  short8 o = {f2bf(a.x), f2bf(a.y), f2bf(a.z), f2bf(a.w),
              f2bf(b.x), f2bf(b.y), f2bf(b.z), f2bf(b.w)};
  *(short8*)(Xb + base) = o;
}

// ---------------- W [K,N] fp32 -> Wt [N,K] bf16 ----------------
__global__ __launch_bounds__(256) void k_cvtw(const float* __restrict__ W0,
                                              const float* __restrict__ W1,
                                              const float* __restrict__ W2,
                                              const float* __restrict__ W3,
                                              short* __restrict__ Wt) {
  __shared__ float T[64][65];
  const float* W = (blockIdx.z == 0) ? W0 : (blockIdx.z == 1) ? W1
                 : (blockIdx.z == 2) ? W2 : W3;
  short* dst = Wt + (size_t)blockIdx.z * HIDDEN * HIDDEN;
  const int n0 = blockIdx.x * 64, k0 = blockIdx.y * 64;
  const int tid = threadIdx.x;
  for (int t = tid; t < 4096; t += 256) {
    int r = t >> 6, c = t & 63;
    T[r][c] = W[(size_t)(k0 + r) * HIDDEN + n0 + c];
  }
  __syncthreads();
  for (int t = tid; t < 4096; t += 256) {
    int r = t >> 6, c = t & 63;
    dst[(size_t)(n0 + r) * HIDDEN + k0 + c] = f2bf(T[c][r]);
  }
}

// ---------------- zero K pad columns 72..95 ----------------
__global__ __launch_bounds__(256) void k_kpad(short* __restrict__ Kp) {
  const int r = blockIdx.x * 256 + threadIdx.x;  // 131072 rows
  const short8 z = {0, 0, 0, 0, 0, 0, 0, 0};
  short* p = Kp + (size_t)r * KSTRIDE + 72;
  *(short8*)(p) = z;
  *(short8*)(p + 8) = z;
  *(short8*)(p + 16) = z;
}

// ---------------- GEMM: C = A[M,K]bf16 @ Wt[N,K]bf16^T + bias ----------------
// OUTKIND 0: bf16 per-head layout [B,H,S,RSTRIDE];  OUTKIND 1: fp32 [M,N]
template <int OUTKIND, int RSTRIDE>
__global__ __launch_bounds__(256) void k_gemm(const short* __restrict__ A,
                                              const short* __restrict__ Bt,
                                              const float* __restrict__ bias,
                                              void* __restrict__ Cout,
                                              float scale) {
  __shared__ __align__(16) short As[8192];  // [128][64] bf16, XOR-swizzled
  __shared__ __align__(16) short Bs[8192];
  const int tid = threadIdx.x;
  const int lane = tid & 63;
  const int wid = tid >> 6;
  const int wr = wid >> 1, wc = wid & 1;
  // XCD-chunked block swizzle (576 = 72*8, bijective)
  const int flat = blockIdx.y * 9 + blockIdx.x;
  const int rid = (flat & 7) * 72 + (flat >> 3);
  const int row0 = (rid / 9) << 7;
  const int col0 = (rid % 9) << 7;
  const int l15 = lane & 15, lh = lane >> 4;
  const int lr8 = lane >> 3;
  const int csrc = ((lane & 7) ^ lr8) << 3;  // pre-swizzled source col (shorts)

  const f32x4 fz = {0.f, 0.f, 0.f, 0.f};
  f32x4 acc[4][4];
#pragma unroll
  for (int m = 0; m < 4; ++m)
#pragma unroll
    for (int n = 0; n < 4; ++n) acc[m][n] = fz;

  for (int k0 = 0; k0 < HIDDEN; k0 += 64) {
#pragma unroll
    for (int i = 0; i < 4; ++i) {
      const int chunk = (wid << 2) + i;
      const int r = (chunk << 3) + lr8;
      gload16(A + (size_t)(row0 + r) * HIDDEN + k0 + csrc, (void*)(As + (chunk << 9)));
      gload16(Bt + (size_t)(col0 + r) * HIDDEN + k0 + csrc, (void*)(Bs + (chunk << 9)));
    }
    __syncthreads();
#pragma unroll
    for (int ks = 0; ks < 2; ++ks) {
      short8 af[4], bfr[4];
#pragma unroll
      for (int m = 0; m < 4; ++m) {
        const int r = (wr << 6) + (m << 4) + l15;
        const int off = ((ks << 6) + (lh << 4)) ^ ((r & 7) << 4);
        af[m] = *(const short8*)((const char*)As + r * 128 + off);
      }
#pragma unroll
      for (int n = 0; n < 4; ++n) {
        const int r = (wc << 6) + (n << 4) + l15;
        const int off = ((ks << 6) + (lh << 4)) ^ ((r & 7) << 4);
        bfr[n] = *(const short8*)((const char*)Bs + r * 128 + off);
      }
      __builtin_amdgcn_s_setprio(1);
#pragma unroll
      for (int m = 0; m < 4; ++m)
#pragma unroll
        for (int n = 0; n < 4; ++n)
          acc[m][n] = __builtin_amdgcn_mfma_f32_16x16x32_bf16(af[m], bfr[n], acc[m][n], 0, 0, 0);
      __builtin_amdgcn_s_setprio(0);
    }
    __syncthreads();
  }

  if (OUTKIND == 0) {
    short* C = (short*)Cout;
#pragma unroll
    for (int n = 0; n < 4; ++n) {
      const int c = col0 + (wc << 6) + (n << 4) + l15;
      const int h = c / 72;
      const int d = c - h * 72;
      const float bv = bias[c];
#pragma unroll
      for (int m = 0; m < 4; ++m)
#pragma unroll
        for (int i = 0; i < 4; ++i) {
          const int r = row0 + (wr << 6) + (m << 4) + (lh << 2) + i;
          const int b = r >> 10, s = r & 1023;
          C[(size_t)((((b << 4) + h) << 10) + s) * RSTRIDE + d] =
              f2bf((acc[m][n][i] + bv) * scale);
        }
    }
  } else {
    float* C = (float*)Cout;
#pragma unroll
    for (int n = 0; n < 4; ++n) {
      const int c = col0 + (wc << 6) + (n << 4) + l15;
      const float bv = bias[c];
#pragma unroll
      for (int m = 0; m < 4; ++m)
#pragma unroll
        for (int i = 0; i < 4; ++i) {
          const int r = row0 + (wr << 6) + (m << 4) + (lh << 2) + i;
          C[(size_t)r * HIDDEN + c] = acc[m][n][i] + bv;
        }
    }
  }
}

// ---------------- V [BH,1024,72] -> Vt [BH,80,1024] (rows 72..79 = 0) --------
__global__ __launch_bounds__(256) void k_vtrans(const short* __restrict__ V,
                                                short* __restrict__ Vt) {
  __shared__ short T[128 * 80];  // [s][d], stride 80 shorts
  const int tid = threadIdx.x;
  const int s0 = blockIdx.x * 128;
  const int bh = blockIdx.y;
  const size_t vbase = (size_t)bh * SEQ * 72;
  for (int t = tid; t < 128 * 9; t += 256) {
    int r = t / 9, ch = t - r * 9;
    *(short8*)(T + r * 80 + ch * 8) =
        *(const short8*)(V + vbase + (size_t)(s0 + r) * 72 + ch * 8);
  }
  __syncthreads();
  const size_t obase = (size_t)bh * 80 * 1024;
  const short8 sz = {0, 0, 0, 0, 0, 0, 0, 0};
  for (int t = tid; t < 80 * 16; t += 256) {
    int sc = t / 80, d = t - sc * 80;
    short8 v = sz;
    if (d < 72) {
#pragma unroll
      for (int j = 0; j < 8; ++j) v[j] = T[(sc * 8 + j) * 80 + d];
    }
    *(short8*)(Vt + obase + (size_t)d * 1024 + s0 + sc * 8) = v;
  }
}

// ---------------- Flash attention (bf16 MFMA, swapped QK^T) ----------------
// grid: 1024 blocks (XCD-chunked -> (qtile, bh)). 4 waves x 32 q-rows. KB=64.
__global__ __launch_bounds__(256, 4) void k_attn(const short* __restrict__ Qg,
                                                 const short* __restrict__ Kp,
                                                 const short* __restrict__ Vt,
                                                 short* __restrict__ Og) {
  __shared__ __align__(16) short Ks[64 * KSTRIDE];  // 13312 B, linear
  __shared__ __align__(16) short Vs[80 * 64];       // 10240 B, XOR-swizzled content
  __shared__ __align__(16) short Ps[4 * 16 * 72];   // 9216 B, per-wave 16 q-rows
  const int tid = threadIdx.x, lane = tid & 63, wid = tid >> 6;
  const int l15 = lane & 15, lh = lane >> 4;
  // XCD-chunked swizzle: 8 qtiles of one bh stay on one XCD
  const int id = blockIdx.x;
  const int rid = (id & 7) * 128 + (id >> 3);
  const int bh = rid >> 3;
  const int q0 = (rid & 7) << 7;
  const short8 sz = {0, 0, 0, 0, 0, 0, 0, 0};
  const f32x4 fz = {0.f, 0.f, 0.f, 0.f};

  // Q fragments in registers (already scaled by 1/sqrt(72) in the Q-GEMM)
  short8 qf[2][3];
#pragma unroll
  for (int m = 0; m < 2; ++m)
#pragma unroll
    for (int ks = 0; ks < 3; ++ks) {
      const int row = q0 + wid * 32 + m * 16 + l15;
      const int e0 = ks * 32 + lh * 8;
      if (e0 < 72)
        qf[m][ks] = *(const short8*)(Qg + ((size_t)bh * 1024 + row) * 72 + e0);
      else
        qf[m][ks] = sz;
    }

  float mrun[2] = {-1e30f, -1e30f};
  float lrun[2] = {0.f, 0.f};
  f32x4 oacc[2][5];
#pragma unroll
  for (int m = 0; m < 2; ++m)
#pragma unroll
    for (int no = 0; no < 5; ++no) oacc[m][no] = fz;

  const char* kgb = (const char*)Kp + ((size_t)bh * 1024) * (KSTRIDE * 2);
  const char* vgb = (const char*)Vt + (size_t)bh * 163840;

  for (int kt = 0; kt < 16; ++kt) {
    // ---- stage K tile: 13 contiguous 1KB wave-chunks ----
    const char* kg = kgb + (size_t)kt * 64 * (KSTRIDE * 2);
    for (int c = wid; c < 13; c += 4)
      gload16(kg + c * 1024 + lane * 16, (char*)Ks + c * 1024);
    // ---- stage V tile: linear LDS, pre-swizzled global source ----
    for (int c = wid; c < 10; c += 4) {
      const int p = c * 1024 + lane * 16;
      const int d = p >> 7;                       // 0..79
      const int sc16 = (lane & 7) ^ (d & 7);      // swizzled source chunk
      gload16(vgb + (size_t)d * 2048 + kt * 128 + sc16 * 16, (char*)Vs + c * 1024);
    }
    __syncthreads();

#pragma unroll
    for (int m = 0; m < 2; ++m) {
      // ---- QK^T swapped: lane holds 16 consecutive keys of q-row l15 ----
      f32x4 sa[4];
#pragma unroll
      for (int n = 0; n < 4; ++n) sa[n] = fz;
#pragma unroll
      for (int ks = 0; ks < 3; ++ks) {
        short8 kf[4];
#pragma unroll
        for (int n = 0; n < 4; ++n)
          kf[n] = *(const short8*)((const char*)Ks + (n * 16 + l15) * 208 + ks * 64 + lh * 16);
        __builtin_amdgcn_s_setprio(1);
#pragma unroll
        for (int n = 0; n < 4; ++n)
          sa[n] = __builtin_amdgcn_mfma_f32_16x16x32_bf16(kf[n], qf[m][ks], sa[n], 0, 0, 0);
        __builtin_amdgcn_s_setprio(0);
      }

      // ---- online softmax (row = q = l15; reduce over lh via 2 shfl) ----
      float mx = sa[0][0];
#pragma unroll
      for (int n = 0; n < 4; ++n)
#pragma unroll
        for (int i = 0; i < 4; ++i) mx = fmaxf(mx, sa[n][i]);
      mx = fmaxf(mx, __shfl_xor(mx, 16));
      mx = fmaxf(mx, __shfl_xor(mx, 32));

      const bool skip = __all(mx <= mrun[m] + 8.0f);
      if (!skip) {
        const float nm = fmaxf(mrun[m], mx);
        const float corr = __expf(mrun[m] - nm);
        lrun[m] *= corr;
        mrun[m] = nm;
        float c0 = __shfl(corr, lh * 4 + 0);
        float c1 = __shfl(corr, lh * 4 + 1);
        float c2 = __shfl(corr, lh * 4 + 2);
        float c3 = __shfl(corr, lh * 4 + 3);
        const f32x4 cv = {c0, c1, c2, c3};
#pragma unroll
        for (int no = 0; no < 5; ++no) oacc[m][no] *= cv;
      }

      float ps = 0.f;
#pragma unroll
      for (int n = 0; n < 4; ++n)
#pragma unroll
        for (int i = 0; i < 4; ++i) {
          const float p = __expf(sa[n][i] - mrun[m]);
          sa[n][i] = p;
          ps += p;
        }
      ps += __shfl_xor(ps, 16);
      ps += __shfl_xor(ps, 32);
      lrun[m] += ps;

      // ---- P -> LDS: pack 4 consecutive keys via v_perm, ds_write_b64 ----
#pragma unroll
      for (int n = 0; n < 4; ++n) {
        unsigned w0 = __builtin_amdgcn_perm(__float_as_uint(sa[n][1]),
                                            __float_as_uint(sa[n][0]), 0x07060302u);
        unsigned w1 = __builtin_amdgcn_perm(__float_as_uint(sa[n][3]),
                                            __float_as_uint(sa[n][2]), 0x07060302u);
        uint2 w = {w0, w1};
        *(uint2*)((char*)Ps + wid * 2304 + l15 * 144 + n * 32 + lh * 8) = w;
      }

      // ---- PV ----
#pragma unroll
      for (int ks = 0; ks < 2; ++ks) {
        const short8 pa = *(const short8*)((const char*)Ps + wid * 2304 + l15 * 144 + ks * 64 + lh * 16);
        short8 vb[5];
        const int cc = ((ks << 2) + lh) ^ (l15 & 7);
#pragma unroll
        for (int no = 0; no < 5; ++no)
          vb[no] = *(const short8*)((const char*)Vs + no * 2048 + l15 * 128 + cc * 16);
        __builtin_amdgcn_s_setprio(1);
#pragma unroll
        for (int no = 0; no < 5; ++no)
          oacc[m][no] = __builtin_amdgcn_mfma_f32_16x16x32_bf16(pa, vb[no], oacc[m][no], 0, 0, 0);
        __builtin_amdgcn_s_setprio(0);
      }
    }
    __syncthreads();
  }

  // ---- epilogue ----
  const int b = bh >> 4, h = bh & 15;
#pragma unroll
  for (int m = 0; m < 2; ++m) {
    const float il = 1.0f / lrun[m];
    float inv[4];
#pragma unroll
    for (int i = 0; i < 4; ++i) inv[i] = __shfl(il, lh * 4 + i);
#pragma unroll
    for (int no = 0; no < 5; ++no) {
      const int d = no * 16 + l15;
      if (d < 72) {
#pragma unroll
        for (int i = 0; i < 4; ++i) {
          const int s = q0 + wid * 32 + m * 16 + lh * 4 + i;
          Og[((size_t)(b * 1024 + s)) * HIDDEN + h * 72 + d] = f2bf(oacc[m][no][i] * inv[i]);
        }
      }
    }
  }
}

// ---------------- launch ----------------
extern "C" void kernel_launch(void* const* d_in, const int* in_sizes, int n_in,
                              void* d_out, int out_size, void* d_ws, size_t ws_size,
                              hipStream_t stream) {
  const float* x  = (const float*)d_in[0];
  const float* wq = (const float*)d_in[1];
  const float* bq = (const float*)d_in[2];
  const float* wk = (const float*)d_in[3];
  const float* bk = (const float*)d_in[4];
  const float* wv = (const float*)d_in[5];
  const float* bv = (const float*)d_in[6];
  const float* wo = (const float*)d_in[7];
  const float* bo = (const float*)d_in[8];

  char* ws = (char*)d_ws;
  short* xb = (short*)ws;                         // 18,874,368 B (also attn out)
  short* wT = (short*)(ws + 18874368);            // 10,616,832 B
  short* Qb = (short*)(ws + 29491200);            // 18,874,368 B
  short* Kp = (short*)(ws + 48365568);            // 27,262,976 B (padded K)
  short* Vb = (short*)(ws + 75628544);            // 18,874,368 B
  short* Vt = (short*)(ws + 94502912);            // 20,971,520 B
  const size_t WSZ = (size_t)HIDDEN * HIDDEN;

  k_kpad<<<512, 256, 0, stream>>>(Kp);
  k_cvtx<<<4608, 256, 0, stream>>>(x, xb);
  k_cvtw<<<dim3(18, 18, 4), 256, 0, stream>>>(wq, wk, wv, wo, wT);

  dim3 gg(9, 64);
  const float qscale = 0.11785113019775793f;  // 1/sqrt(72)
  k_gemm<0, 72><<<gg, 256, 0, stream>>>(xb, wT + 0 * WSZ, bq, (void*)Qb, qscale);
  k_gemm<0, KSTRIDE><<<gg, 256, 0, stream>>>(xb, wT + 1 * WSZ, bk, (void*)Kp, 1.0f);
  k_gemm<0, 72><<<gg, 256, 0, stream>>>(xb, wT + 2 * WSZ, bv, (void*)Vb, 1.0f);

  k_vtrans<<<dim3(8, 128), 256, 0, stream>>>(Vb, Vt);
  k_attn<<<1024, 256, 0, stream>>>(Qb, Kp, Vt, xb);

  k_gemm<1, 0><<<gg, 256, 0, stream>>>(xb, wT + 3 * WSZ, bo, d_out, 1.0f);
}